// Round 2
// baseline (352.537 us; speedup 1.0000x reference)
//
#include <hip/hip_runtime.h>

#define N_NODES 50000
#define N_EDGES 200000
#define IN1_SIZE 160
#define IN2_SIZE 4
#define W_SIZE 224
#define OUT_SIZE 480
#define INV_SQRT3 0.5773502691896258f
#define INV_SQRT2 0.7071067811865476f

// ---------- shared per-edge message math ----------
// Value of flat output element `idx` (0..479) for one edge.
__device__ __forceinline__ float edge_val(
    int idx, const float* __restrict__ x, const float* __restrict__ w,
    float y0, float y1x, float y1y, float y1z)
{
    if (idx < 64) {
        return w[idx] * x[idx] * y0;                       // p1
    } else if (idx < 96) {
        const int u = idx - 64;                            // p4
        const float a0 = x[64 + 3 * u + 0];
        const float a1 = x[64 + 3 * u + 1];
        const float a2 = x[64 + 3 * u + 2];
        return w[160 + u] * (a0 * y1x + a1 * y1y + a2 * y1z) * INV_SQRT3;
    } else if (idx < 288) {
        const int t = idx - 96;                            // p2
        const int i = t / 3;
        const int k = t - 3 * i;
        const float yk = (k == 0) ? y1x : (k == 1) ? y1y : y1z;
        return w[64 + i] * x[i] * yk;
    } else if (idx < 384) {
        const int t = idx - 288;                           // p3
        const int u = t / 3;
        const int k = t - 3 * u;
        return w[128 + u] * x[64 + 3 * u + k] * y0;
    } else {
        const int t = idx - 384;                           // p5 (cross)
        const int u = t / 3;
        const int k = t - 3 * u;
        const float a0 = x[64 + 3 * u + 0];
        const float a1 = x[64 + 3 * u + 1];
        const float a2 = x[64 + 3 * u + 2];
        float c;
        if (k == 0)      c = a1 * y1z - a2 * y1y;
        else if (k == 1) c = a2 * y1x - a0 * y1z;
        else             c = a0 * y1y - a1 * y1x;
        return w[192 + u] * c * INV_SQRT2;
    }
}

// ---------- CSR build ----------
__global__ void hist_kernel(const int* __restrict__ dst, int* __restrict__ counts) {
    int i = blockIdx.x * blockDim.x + threadIdx.x;
    if (i < N_EDGES) atomicAdd(&counts[dst[i]], 1);
}

// Single-block exclusive scan of counts[N_NODES] -> offsets, cursor.
__global__ __launch_bounds__(1024) void scan_kernel(
    const int* __restrict__ counts, int* __restrict__ offsets, int* __restrict__ cursor)
{
    __shared__ int partial[1024];
    const int C = (N_NODES + 1023) / 1024;  // 49
    const int t = threadIdx.x;
    const int base = t * C;
    int s = 0;
    for (int i = 0; i < C; ++i) {
        int idx = base + i;
        if (idx < N_NODES) s += counts[idx];
    }
    partial[t] = s;
    __syncthreads();
    for (int off = 1; off < 1024; off <<= 1) {
        int v = (t >= off) ? partial[t - off] : 0;
        __syncthreads();
        partial[t] += v;
        __syncthreads();
    }
    int run = (t == 0) ? 0 : partial[t - 1];
    for (int i = 0; i < C; ++i) {
        int idx = base + i;
        if (idx < N_NODES) {
            offsets[idx] = run;
            cursor[idx]  = run;
            run += counts[idx];
        }
    }
}

__global__ void fill_kernel(const int* __restrict__ dst, int* __restrict__ cursor,
                            int* __restrict__ edgelist) {
    int i = blockIdx.x * blockDim.x + threadIdx.x;
    if (i < N_EDGES) {
        int pos = atomicAdd(&cursor[dst[i]], 1);
        edgelist[pos] = i;
    }
}

// ---------- gather: one wave per node, no atomics ----------
__global__ __launch_bounds__(256) void tp_gather_kernel(
    const float* __restrict__ in1,
    const float* __restrict__ in2,
    const float* __restrict__ weight,
    const int*   __restrict__ src,
    const int*   __restrict__ offsets,
    const int*   __restrict__ counts,
    const int*   __restrict__ edgelist,
    float*       __restrict__ out)
{
    const int wave = threadIdx.x >> 6;
    const int lane = threadIdx.x & 63;
    const int n = blockIdx.x * 4 + wave;
    if (n >= N_NODES) return;

    const int start = offsets[n];
    const int deg   = counts[n];

    float acc[8];
    #pragma unroll
    for (int j = 0; j < 8; ++j) acc[j] = 0.f;

    for (int t = 0; t < deg; ++t) {
        const int e  = edgelist[start + t];
        const int sn = src[e];
        const float* __restrict__ x = in1 + (long)sn * IN1_SIZE;
        const float* __restrict__ w = weight + (long)e * W_SIZE;
        const float y0  = in2[e * 4 + 0];
        const float y1x = in2[e * 4 + 1];
        const float y1y = in2[e * 4 + 2];
        const float y1z = in2[e * 4 + 3];

        #pragma unroll
        for (int j = 0; j < 8; ++j) {
            const int idx = lane + (j << 6);
            if (idx < OUT_SIZE)
                acc[j] += edge_val(idx, x, w, y0, y1x, y1y, y1z);
        }
    }

    float* __restrict__ o = out + (long)n * OUT_SIZE;
    #pragma unroll
    for (int j = 0; j < 8; ++j) {
        const int idx = lane + (j << 6);
        if (idx < OUT_SIZE) o[idx] = acc[j];
    }
}

// ---------- fallback path (R1, atomics) ----------
__global__ void zero_out_kernel(float4* __restrict__ out, int n4) {
    const float4 z = make_float4(0.f, 0.f, 0.f, 0.f);
    for (int i = blockIdx.x * blockDim.x + threadIdx.x; i < n4;
         i += gridDim.x * blockDim.x) out[i] = z;
}

__global__ __launch_bounds__(256) void tp_scatter_kernel(
    const float* __restrict__ in1,
    const float* __restrict__ in2,
    const float* __restrict__ weight,
    const int*   __restrict__ src,
    const int*   __restrict__ dst,
    float*       __restrict__ out)
{
    const int wave = threadIdx.x >> 6;
    const int lane = threadIdx.x & 63;
    const int e = blockIdx.x * 4 + wave;
    if (e >= N_EDGES) return;

    const int sn = src[e];
    const int dn = dst[e];
    const float* __restrict__ x = in1 + (long)sn * IN1_SIZE;
    const float* __restrict__ w = weight + (long)e * W_SIZE;
    const float y0  = in2[e * 4 + 0];
    const float y1x = in2[e * 4 + 1];
    const float y1y = in2[e * 4 + 2];
    const float y1z = in2[e * 4 + 3];
    float* __restrict__ o = out + (long)dn * OUT_SIZE;

    #pragma unroll
    for (int j = 0; j < 8; ++j) {
        const int idx = lane + (j << 6);
        if (idx < OUT_SIZE)
            atomicAdd(o + idx, edge_val(idx, x, w, y0, y1x, y1y, y1z));
    }
}

extern "C" void kernel_launch(void* const* d_in, const int* in_sizes, int n_in,
                              void* d_out, int out_size, void* d_ws, size_t ws_size,
                              hipStream_t stream) {
    const float* in1    = (const float*)d_in[0];
    const float* in2    = (const float*)d_in[1];
    const float* weight = (const float*)d_in[2];
    const int*   src    = (const int*)d_in[3];
    const int*   dst    = (const int*)d_in[4];
    float* out = (float*)d_out;

    // ws layout: counts[50000] | offsets[50000] | cursor[50000] | edgelist[200000]
    const size_t need = (size_t)(3 * N_NODES + N_EDGES) * sizeof(int);
    if (ws_size >= need) {
        int* counts   = (int*)d_ws;
        int* offsets  = counts + N_NODES;
        int* cursor   = offsets + N_NODES;
        int* edgelist = cursor + N_NODES;

        hipMemsetAsync(counts, 0, N_NODES * sizeof(int), stream);
        hist_kernel<<<(N_EDGES + 255) / 256, 256, 0, stream>>>(dst, counts);
        scan_kernel<<<1, 1024, 0, stream>>>(counts, offsets, cursor);
        fill_kernel<<<(N_EDGES + 255) / 256, 256, 0, stream>>>(dst, cursor, edgelist);

        const int blocks = (N_NODES + 3) / 4;  // one wave per node
        tp_gather_kernel<<<blocks, 256, 0, stream>>>(
            in1, in2, weight, src, offsets, counts, edgelist, out);
    } else {
        // Fallback: proven atomic scatter path.
        const int n4 = out_size / 4;
        zero_out_kernel<<<2048, 256, 0, stream>>>((float4*)out, n4);
        const int blocks = (N_EDGES + 3) / 4;
        tp_scatter_kernel<<<blocks, 256, 0, stream>>>(in1, in2, weight, src, dst, out);
    }
}

// Round 3
// 337.545 us; speedup vs baseline: 1.0444x; 1.0444x over previous
//
#include <hip/hip_runtime.h>

#define N_NODES 50000
#define N_EDGES 200000
#define IN1_SIZE 160
#define W_SIZE 224
#define OUT_SIZE 480
#define RCHUNK 8
#define INV_SQRT3 0.5773502691896258f
#define INV_SQRT2 0.7071067811865476f

// ---------------- CSR build ----------------
__global__ void hist_kernel(const int* __restrict__ dst, int* __restrict__ counts) {
    int i = blockIdx.x * blockDim.x + threadIdx.x;
    if (i < N_EDGES) atomicAdd(&counts[dst[i]], 1);
}

__global__ __launch_bounds__(1024) void scan_kernel(
    const int* __restrict__ counts, int* __restrict__ offsets, int* __restrict__ cursor)
{
    __shared__ int partial[1024];
    const int C = (N_NODES + 1023) / 1024;  // 49
    const int t = threadIdx.x;
    const int base = t * C;
    int s = 0;
    for (int i = 0; i < C; ++i) {
        int idx = base + i;
        if (idx < N_NODES) s += counts[idx];
    }
    partial[t] = s;
    __syncthreads();
    for (int off = 1; off < 1024; off <<= 1) {
        int v = (t >= off) ? partial[t - off] : 0;
        __syncthreads();
        partial[t] += v;
        __syncthreads();
    }
    int run = (t == 0) ? 0 : partial[t - 1];
    for (int i = 0; i < C; ++i) {
        int idx = base + i;
        if (idx < N_NODES) {
            offsets[idx] = run;
            cursor[idx]  = run;
            run += counts[idx];
        }
    }
}

__global__ void fill_kernel(const int* __restrict__ dst, const int* __restrict__ src,
                            int* __restrict__ cursor, int* __restrict__ edgelist,
                            int* __restrict__ ds, int* __restrict__ ss) {
    int i = blockIdx.x * blockDim.x + threadIdx.x;
    if (i < N_EDGES) {
        int d = dst[i];
        int pos = atomicAdd(&cursor[d], 1);
        edgelist[pos] = i;
        ds[pos] = d;
        ss[pos] = src[i];
    }
}

// Zero only rows that receive atomic adds (segment crosses a chunk boundary)
// or have no edges at all. Rows flushed by plain store are fully overwritten.
__global__ __launch_bounds__(256) void zero_rows_kernel(
    const int* __restrict__ counts, const int* __restrict__ offsets,
    float* __restrict__ out)
{
    const int wave = threadIdx.x >> 6;
    const int lane = threadIdx.x & 63;
    const int n = blockIdx.x * 4 + wave;
    if (n >= N_NODES) return;
    const int cnt = counts[n];
    const int start = offsets[n];
    const bool nz = (cnt == 0) || ((start >> 3) != ((start + cnt - 1) >> 3));
    if (!nz) return;
    float* __restrict__ row = out + (long)n * OUT_SIZE;
    #pragma unroll
    for (int j = 0; j < 8; ++j) {
        const int idx = lane + (j << 6);
        if (idx < OUT_SIZE) row[idx] = 0.f;
    }
}

// ---------------- main: chunk-of-8 sorted edges per wave ----------------
__global__ __launch_bounds__(256) void tp_seg_kernel(
    const float* __restrict__ in1,
    const float* __restrict__ in2,
    const float* __restrict__ weight,
    const int*   __restrict__ edgelist,
    const int*   __restrict__ ds,
    const int*   __restrict__ ss,
    float*       __restrict__ out)
{
    const int wave = threadIdx.x >> 6;
    const int lane = threadIdx.x & 63;
    const int wid = blockIdx.x * 4 + wave;
    const int p0 = wid * RCHUNK;
    if (p0 >= N_EDGES) return;
    const int u = lane & 31;
    const int h = lane >> 5;

    // ---- load phase: everything independent, issued up-front ----
    int e_[RCHUNK], dn_[RCHUNK], sn_[RCHUNK];
    #pragma unroll
    for (int t = 0; t < RCHUNK; ++t) {
        e_[t]  = edgelist[p0 + t];
        dn_[t] = ds[p0 + t];
        sn_[t] = ss[p0 + t];
    }
    float y_[RCHUNK][4];
    #pragma unroll
    for (int t = 0; t < RCHUNK; ++t) {
        const float* __restrict__ y = in2 + 4 * e_[t];
        y_[t][0] = y[0]; y_[t][1] = y[1]; y_[t][2] = y[2]; y_[t][3] = y[3];
    }
    float xs_[RCHUNK], w1_[RCHUNK], w2_[RCHUNK], w3_[RCHUNK], w4_[RCHUNK], w5_[RCHUNK];
    float v_[RCHUNK][3];
    #pragma unroll
    for (int t = 0; t < RCHUNK; ++t) {
        const float* __restrict__ x = in1 + (long)sn_[t] * IN1_SIZE;
        const float* __restrict__ w = weight + (long)e_[t] * W_SIZE;
        xs_[t]   = x[lane];
        w1_[t]   = w[lane];
        w2_[t]   = w[64 + lane];
        v_[t][0] = x[64 + 3 * u];
        v_[t][1] = x[65 + 3 * u];
        v_[t][2] = x[66 + 3 * u];
        w3_[t]   = w[128 + u];
        w4_[t]   = w[160 + u];
        w5_[t]   = w[192 + u];
    }

    // precomputed flat output offsets for this lane (new mapping, no div/mod):
    //  acc0 -> p1[lane]            @ lane
    //  acc1..3 -> p2[lane][0..2]   @ 96+3*lane+k
    //  h==0: acc4 -> p4[u] @ 64+u ; acc5..7 -> p3[u][0..2] @ 288+3u+k
    //  h==1:                         acc5..7 -> p5[u][0..2] @ 384+3u+k
    const int off0 = lane;
    const int off1 = 96 + 3 * lane;
    const int off4 = 64 + u;
    const int off5 = (h ? 384 : 288) + 3 * u;

    const int head = (p0 > 0) ? ds[p0 - 1] : -1;
    const int tail = (p0 + RCHUNK < N_EDGES) ? ds[p0 + RCHUNK] : -1;
    const bool head_shared = (head == dn_[0]);
    const bool tail_shared = (tail == dn_[RCHUNK - 1]);

    float acc[8];
    #pragma unroll
    for (int j = 0; j < 8; ++j) acc[j] = 0.f;

    auto flush = [&](int node, bool use_atomic) {
        float* __restrict__ row = out + (long)node * OUT_SIZE;
        if (use_atomic) {
            atomicAdd(row + off0,     acc[0]);
            atomicAdd(row + off1,     acc[1]);
            atomicAdd(row + off1 + 1, acc[2]);
            atomicAdd(row + off1 + 2, acc[3]);
            if (h == 0) atomicAdd(row + off4, acc[4]);
            atomicAdd(row + off5,     acc[5]);
            atomicAdd(row + off5 + 1, acc[6]);
            atomicAdd(row + off5 + 2, acc[7]);
        } else {
            row[off0]     = acc[0];
            row[off1]     = acc[1];
            row[off1 + 1] = acc[2];
            row[off1 + 2] = acc[3];
            if (h == 0) row[off4] = acc[4];
            row[off5]     = acc[5];
            row[off5 + 1] = acc[6];
            row[off5 + 2] = acc[7];
        }
        #pragma unroll
        for (int j = 0; j < 8; ++j) acc[j] = 0.f;
    };

    int cur = dn_[0];
    bool first = true;

    #pragma unroll
    for (int t = 0; t < RCHUNK; ++t) {
        if (dn_[t] != cur) {
            flush(cur, first && head_shared);
            first = false;
            cur = dn_[t];
        }
        const float y0 = y_[t][0], yx = y_[t][1], yy = y_[t][2], yz = y_[t][3];
        acc[0] += w1_[t] * xs_[t] * y0;
        const float sw2 = w2_[t] * xs_[t];
        acc[1] += sw2 * yx;
        acc[2] += sw2 * yy;
        acc[3] += sw2 * yz;
        const float v0 = v_[t][0], v1 = v_[t][1], v2 = v_[t][2];
        if (h == 0) {
            acc[4] += w4_[t] * (v0 * yx + v1 * yy + v2 * yz) * INV_SQRT3;
            const float wy = w3_[t] * y0;
            acc[5] += wy * v0;
            acc[6] += wy * v1;
            acc[7] += wy * v2;
        } else {
            const float wc = w5_[t] * INV_SQRT2;
            acc[5] += wc * (v1 * yz - v2 * yy);
            acc[6] += wc * (v2 * yx - v0 * yz);
            acc[7] += wc * (v0 * yy - v1 * yx);
        }
    }
    flush(cur, (first && head_shared) || tail_shared);
}

// ---------------- fallback path (R1, atomics, no ws needed) ----------------
__global__ void zero_out_kernel(float4* __restrict__ out, int n4) {
    const float4 z = make_float4(0.f, 0.f, 0.f, 0.f);
    for (int i = blockIdx.x * blockDim.x + threadIdx.x; i < n4;
         i += gridDim.x * blockDim.x) out[i] = z;
}

__device__ __forceinline__ float edge_val(
    int idx, const float* __restrict__ x, const float* __restrict__ w,
    float y0, float y1x, float y1y, float y1z)
{
    if (idx < 64) {
        return w[idx] * x[idx] * y0;
    } else if (idx < 96) {
        const int u = idx - 64;
        const float a0 = x[64 + 3 * u + 0];
        const float a1 = x[64 + 3 * u + 1];
        const float a2 = x[64 + 3 * u + 2];
        return w[160 + u] * (a0 * y1x + a1 * y1y + a2 * y1z) * INV_SQRT3;
    } else if (idx < 288) {
        const int t = idx - 96;
        const int i = t / 3;
        const int k = t - 3 * i;
        const float yk = (k == 0) ? y1x : (k == 1) ? y1y : y1z;
        return w[64 + i] * x[i] * yk;
    } else if (idx < 384) {
        const int t = idx - 288;
        const int u = t / 3;
        const int k = t - 3 * u;
        return w[128 + u] * x[64 + 3 * u + k] * y0;
    } else {
        const int t = idx - 384;
        const int u = t / 3;
        const int k = t - 3 * u;
        const float a0 = x[64 + 3 * u + 0];
        const float a1 = x[64 + 3 * u + 1];
        const float a2 = x[64 + 3 * u + 2];
        float c;
        if (k == 0)      c = a1 * y1z - a2 * y1y;
        else if (k == 1) c = a2 * y1x - a0 * y1z;
        else             c = a0 * y1y - a1 * y1x;
        return w[192 + u] * c * INV_SQRT2;
    }
}

__global__ __launch_bounds__(256) void tp_scatter_kernel(
    const float* __restrict__ in1, const float* __restrict__ in2,
    const float* __restrict__ weight,
    const int* __restrict__ src, const int* __restrict__ dst,
    float* __restrict__ out)
{
    const int wave = threadIdx.x >> 6;
    const int lane = threadIdx.x & 63;
    const int e = blockIdx.x * 4 + wave;
    if (e >= N_EDGES) return;
    const int sn = src[e];
    const int dn = dst[e];
    const float* __restrict__ x = in1 + (long)sn * IN1_SIZE;
    const float* __restrict__ w = weight + (long)e * W_SIZE;
    const float y0  = in2[e * 4 + 0];
    const float y1x = in2[e * 4 + 1];
    const float y1y = in2[e * 4 + 2];
    const float y1z = in2[e * 4 + 3];
    float* __restrict__ o = out + (long)dn * OUT_SIZE;
    #pragma unroll
    for (int j = 0; j < 8; ++j) {
        const int idx = lane + (j << 6);
        if (idx < OUT_SIZE)
            atomicAdd(o + idx, edge_val(idx, x, w, y0, y1x, y1y, y1z));
    }
}

extern "C" void kernel_launch(void* const* d_in, const int* in_sizes, int n_in,
                              void* d_out, int out_size, void* d_ws, size_t ws_size,
                              hipStream_t stream) {
    const float* in1    = (const float*)d_in[0];
    const float* in2    = (const float*)d_in[1];
    const float* weight = (const float*)d_in[2];
    const int*   src    = (const int*)d_in[3];
    const int*   dst    = (const int*)d_in[4];
    float* out = (float*)d_out;

    // ws: counts[50k] | offsets[50k] | cursor[50k] | edgelist[200k] | ds[200k] | ss[200k]
    const size_t need = (size_t)(3 * N_NODES + 3 * N_EDGES) * sizeof(int);
    if (ws_size >= need) {
        int* counts   = (int*)d_ws;
        int* offsets  = counts + N_NODES;
        int* cursor   = offsets + N_NODES;
        int* edgelist = cursor + N_NODES;
        int* ds       = edgelist + N_EDGES;
        int* ss       = ds + N_EDGES;

        hipMemsetAsync(counts, 0, N_NODES * sizeof(int), stream);
        hist_kernel<<<(N_EDGES + 255) / 256, 256, 0, stream>>>(dst, counts);
        scan_kernel<<<1, 1024, 0, stream>>>(counts, offsets, cursor);
        fill_kernel<<<(N_EDGES + 255) / 256, 256, 0, stream>>>(dst, src, cursor,
                                                               edgelist, ds, ss);
        zero_rows_kernel<<<(N_NODES + 3) / 4, 256, 0, stream>>>(counts, offsets, out);

        const int nwaves = N_EDGES / RCHUNK;            // 25000
        tp_seg_kernel<<<(nwaves + 3) / 4, 256, 0, stream>>>(
            in1, in2, weight, edgelist, ds, ss, out);
    } else {
        const int n4 = out_size / 4;
        zero_out_kernel<<<2048, 256, 0, stream>>>((float4*)out, n4);
        tp_scatter_kernel<<<(N_EDGES + 3) / 4, 256, 0, stream>>>(
            in1, in2, weight, src, dst, out);
    }
}

// Round 4
// 156.885 us; speedup vs baseline: 2.2471x; 2.1515x over previous
//
#include <hip/hip_runtime.h>

#define N_NODES 50000
#define N_EDGES 200000
#define IN1_SIZE 160
#define W_SIZE 224
#define OUT_SIZE 480
#define BATCH 4
#define INV_SQRT3 0.5773502691896258f
#define INV_SQRT2 0.7071067811865476f

// ---------------- CSR build ----------------
__global__ void hist_kernel(const int* __restrict__ dst, int* __restrict__ counts) {
    int i = blockIdx.x * blockDim.x + threadIdx.x;
    if (i < N_EDGES) atomicAdd(&counts[dst[i]], 1);
}

// Block-level exclusive scan (1024/block, coalesced) + per-block totals.
__global__ __launch_bounds__(1024) void scan_blocks_kernel(
    const int* __restrict__ counts, int* __restrict__ offsets,
    int* __restrict__ partials)
{
    __shared__ int sm[1024];
    const int t = threadIdx.x;
    const int gid = blockIdx.x * 1024 + t;
    const int v = (gid < N_NODES) ? counts[gid] : 0;
    sm[t] = v;
    __syncthreads();
    for (int off = 1; off < 1024; off <<= 1) {
        int a = (t >= off) ? sm[t - off] : 0;
        __syncthreads();
        sm[t] += a;
        __syncthreads();
    }
    if (gid < N_NODES) offsets[gid] = sm[t] - v;   // exclusive within block
    if (t == 1023) partials[blockIdx.x] = sm[1023];
}

// Add prefix of block partials; init cursor. (<=49 partials, redundant loop is L2-hot)
__global__ __launch_bounds__(1024) void add_partials_kernel(
    const int* __restrict__ partials, int* __restrict__ offsets,
    int* __restrict__ cursor)
{
    const int blk = blockIdx.x;
    const int gid = blk * 1024 + threadIdx.x;
    int s = 0;
    for (int j = 0; j < blk; ++j) s += partials[j];
    if (gid < N_NODES) {
        const int o = offsets[gid] + s;
        offsets[gid] = o;
        cursor[gid]  = o;
    }
}

// Scatter edge ids + src + reordered in2 rows into dst-grouped order.
__global__ void fill_kernel(const int* __restrict__ dst, const int* __restrict__ src,
                            const float4* __restrict__ in2,
                            int* __restrict__ cursor, int* __restrict__ edgelist,
                            int* __restrict__ ss, float4* __restrict__ ys) {
    int i = blockIdx.x * blockDim.x + threadIdx.x;
    if (i < N_EDGES) {
        int pos = atomicAdd(&cursor[dst[i]], 1);
        edgelist[pos] = i;
        ss[pos] = src[i];
        ys[pos] = in2[i];
    }
}

// ---------------- main: one wave per node, batched loads, no atomics ----------------
__global__ __launch_bounds__(256) void tp_gather2_kernel(
    const float*  __restrict__ in1,
    const float*  __restrict__ weight,
    const int*    __restrict__ offsets,
    const int*    __restrict__ edgelist,
    const int*    __restrict__ ss,
    const float4* __restrict__ ys,
    float*        __restrict__ out)
{
    const int wave = threadIdx.x >> 6;
    const int lane = threadIdx.x & 63;
    const int n = blockIdx.x * 4 + wave;
    if (n >= N_NODES) return;
    const int u = lane & 31;
    const int h = lane >> 5;

    const int start = offsets[n];
    const int end   = (n + 1 < N_NODES) ? offsets[n + 1] : N_EDGES;
    const int deg   = end - start;

    float acc0 = 0.f, acc1 = 0.f, acc2 = 0.f, acc3 = 0.f;
    float acc4 = 0.f, acc5 = 0.f, acc6 = 0.f, acc7 = 0.f;

    for (int base = 0; base < deg; base += BATCH) {
        const int m = deg - base;   // wave-uniform

        int e_[BATCH], sn_[BATCH];
        float4 y_[BATCH];
        #pragma unroll
        for (int t = 0; t < BATCH; ++t) if (t < m) {
            const int p = start + base + t;
            e_[t]  = edgelist[p];
            sn_[t] = ss[p];
            y_[t]  = ys[p];
        }

        float xs[BATCH], w1[BATCH], w2[BATCH], w3[BATCH], w4[BATCH], w5[BATCH];
        float v0[BATCH], v1[BATCH], v2[BATCH];
        #pragma unroll
        for (int t = 0; t < BATCH; ++t) if (t < m) {
            const float* __restrict__ x = in1 + (long)sn_[t] * IN1_SIZE;
            const float* __restrict__ w = weight + (long)e_[t] * W_SIZE;
            xs[t] = x[lane];
            v0[t] = x[64 + 3 * u];
            v1[t] = x[65 + 3 * u];
            v2[t] = x[66 + 3 * u];
            w1[t] = w[lane];
            w2[t] = w[64 + lane];
            w3[t] = w[128 + u];
            w4[t] = w[160 + u];
            w5[t] = w[192 + u];
        }

        #pragma unroll
        for (int t = 0; t < BATCH; ++t) if (t < m) {
            const float y0 = y_[t].x, yx = y_[t].y, yy = y_[t].z, yz = y_[t].w;
            acc0 += w1[t] * xs[t] * y0;
            const float sw2 = w2[t] * xs[t];
            acc1 += sw2 * yx;
            acc2 += sw2 * yy;
            acc3 += sw2 * yz;
            if (h == 0) {
                acc4 += w4[t] * (v0[t] * yx + v1[t] * yy + v2[t] * yz) * INV_SQRT3;
                const float wy = w3[t] * y0;
                acc5 += wy * v0[t];
                acc6 += wy * v1[t];
                acc7 += wy * v2[t];
            } else {
                const float wc = w5[t] * INV_SQRT2;
                acc5 += wc * (v1[t] * yz - v2[t] * yy);
                acc6 += wc * (v2[t] * yx - v0[t] * yz);
                acc7 += wc * (v0[t] * yy - v1[t] * yx);
            }
        }
    }

    // store: row written exactly once (zeros if deg==0)
    float* __restrict__ row = out + (long)n * OUT_SIZE;
    row[lane]          = acc0;
    row[96 + 3 * lane] = acc1;
    row[97 + 3 * lane] = acc2;
    row[98 + 3 * lane] = acc3;
    if (h == 0) {
        row[64 + u]       = acc4;
        row[288 + 3 * u]  = acc5;
        row[289 + 3 * u]  = acc6;
        row[290 + 3 * u]  = acc7;
    } else {
        row[384 + 3 * u]  = acc5;
        row[385 + 3 * u]  = acc6;
        row[386 + 3 * u]  = acc7;
    }
}

// ---------------- fallback path (R1, atomics, no ws needed) ----------------
__global__ void zero_out_kernel(float4* __restrict__ out, int n4) {
    const float4 z = make_float4(0.f, 0.f, 0.f, 0.f);
    for (int i = blockIdx.x * blockDim.x + threadIdx.x; i < n4;
         i += gridDim.x * blockDim.x) out[i] = z;
}

__device__ __forceinline__ float edge_val(
    int idx, const float* __restrict__ x, const float* __restrict__ w,
    float y0, float y1x, float y1y, float y1z)
{
    if (idx < 64) {
        return w[idx] * x[idx] * y0;
    } else if (idx < 96) {
        const int u = idx - 64;
        const float a0 = x[64 + 3 * u], a1 = x[65 + 3 * u], a2 = x[66 + 3 * u];
        return w[160 + u] * (a0 * y1x + a1 * y1y + a2 * y1z) * INV_SQRT3;
    } else if (idx < 288) {
        const int t = idx - 96;
        const int i = t / 3;
        const int k = t - 3 * i;
        const float yk = (k == 0) ? y1x : (k == 1) ? y1y : y1z;
        return w[64 + i] * x[i] * yk;
    } else if (idx < 384) {
        const int t = idx - 288;
        const int u = t / 3;
        const int k = t - 3 * u;
        return w[128 + u] * x[64 + 3 * u + k] * y0;
    } else {
        const int t = idx - 384;
        const int u = t / 3;
        const int k = t - 3 * u;
        const float a0 = x[64 + 3 * u], a1 = x[65 + 3 * u], a2 = x[66 + 3 * u];
        float c;
        if (k == 0)      c = a1 * y1z - a2 * y1y;
        else if (k == 1) c = a2 * y1x - a0 * y1z;
        else             c = a0 * y1y - a1 * y1x;
        return w[192 + u] * c * INV_SQRT2;
    }
}

__global__ __launch_bounds__(256) void tp_scatter_kernel(
    const float* __restrict__ in1, const float* __restrict__ in2,
    const float* __restrict__ weight,
    const int* __restrict__ src, const int* __restrict__ dst,
    float* __restrict__ out)
{
    const int wave = threadIdx.x >> 6;
    const int lane = threadIdx.x & 63;
    const int e = blockIdx.x * 4 + wave;
    if (e >= N_EDGES) return;
    const int sn = src[e];
    const int dn = dst[e];
    const float* __restrict__ x = in1 + (long)sn * IN1_SIZE;
    const float* __restrict__ w = weight + (long)e * W_SIZE;
    const float y0  = in2[e * 4 + 0];
    const float y1x = in2[e * 4 + 1];
    const float y1y = in2[e * 4 + 2];
    const float y1z = in2[e * 4 + 3];
    float* __restrict__ o = out + (long)dn * OUT_SIZE;
    #pragma unroll
    for (int j = 0; j < 8; ++j) {
        const int idx = lane + (j << 6);
        if (idx < OUT_SIZE)
            atomicAdd(o + idx, edge_val(idx, x, w, y0, y1x, y1y, y1z));
    }
}

extern "C" void kernel_launch(void* const* d_in, const int* in_sizes, int n_in,
                              void* d_out, int out_size, void* d_ws, size_t ws_size,
                              hipStream_t stream) {
    const float* in1    = (const float*)d_in[0];
    const float* in2    = (const float*)d_in[1];
    const float* weight = (const float*)d_in[2];
    const int*   src    = (const int*)d_in[3];
    const int*   dst    = (const int*)d_in[4];
    float* out = (float*)d_out;

    // ws layout (16B-aligned first):
    //   ys[N_EDGES] float4 | counts[N] | offsets[N] | cursor[N] | edgelist[E] | ss[E] | partials[64]
    const size_t need = (size_t)N_EDGES * 16 +
                        (size_t)(3 * N_NODES + 2 * N_EDGES + 64) * sizeof(int);
    if (ws_size >= need) {
        float4* ys     = (float4*)d_ws;
        int* counts    = (int*)(ys + N_EDGES);
        int* offsets   = counts + N_NODES;
        int* cursor    = offsets + N_NODES;
        int* edgelist  = cursor + N_NODES;
        int* ss        = edgelist + N_EDGES;
        int* partials  = ss + N_EDGES;

        const int nblk = (N_NODES + 1023) / 1024;   // 49

        hipMemsetAsync(counts, 0, N_NODES * sizeof(int), stream);
        hist_kernel<<<(N_EDGES + 255) / 256, 256, 0, stream>>>(dst, counts);
        scan_blocks_kernel<<<nblk, 1024, 0, stream>>>(counts, offsets, partials);
        add_partials_kernel<<<nblk, 1024, 0, stream>>>(partials, offsets, cursor);
        fill_kernel<<<(N_EDGES + 255) / 256, 256, 0, stream>>>(
            dst, src, (const float4*)in2, cursor, edgelist, ss, ys);

        tp_gather2_kernel<<<(N_NODES + 3) / 4, 256, 0, stream>>>(
            in1, weight, offsets, edgelist, ss, ys, out);
    } else {
        const int n4 = out_size / 4;
        zero_out_kernel<<<2048, 256, 0, stream>>>((float4*)out, n4);
        tp_scatter_kernel<<<(N_EDGES + 3) / 4, 256, 0, stream>>>(
            in1, in2, weight, src, dst, out);
    }
}

// Round 5
// 152.085 us; speedup vs baseline: 2.3180x; 1.0316x over previous
//
#include <hip/hip_runtime.h>

#define N_NODES 50000
#define N_EDGES 200000
#define IN1_SIZE 160
#define W_SIZE 224
#define OUT_SIZE 480
#define INV_SQRT3 0.5773502691896258f
#define INV_SQRT2 0.7071067811865476f

// ---------------- CSR build ----------------
__global__ void hist_kernel(const int* __restrict__ dst, int* __restrict__ counts) {
    int i = blockIdx.x * blockDim.x + threadIdx.x;
    if (i < N_EDGES) atomicAdd(&counts[dst[i]], 1);
}

__global__ __launch_bounds__(1024) void scan_blocks_kernel(
    const int* __restrict__ counts, int* __restrict__ offsets,
    int* __restrict__ partials)
{
    __shared__ int sm[1024];
    const int t = threadIdx.x;
    const int gid = blockIdx.x * 1024 + t;
    const int v = (gid < N_NODES) ? counts[gid] : 0;
    sm[t] = v;
    __syncthreads();
    for (int off = 1; off < 1024; off <<= 1) {
        int a = (t >= off) ? sm[t - off] : 0;
        __syncthreads();
        sm[t] += a;
        __syncthreads();
    }
    if (gid < N_NODES) offsets[gid] = sm[t] - v;
    if (t == 1023) partials[blockIdx.x] = sm[1023];
}

__global__ __launch_bounds__(1024) void add_partials_kernel(
    const int* __restrict__ partials, int* __restrict__ offsets,
    int* __restrict__ cursor)
{
    const int blk = blockIdx.x;
    const int gid = blk * 1024 + threadIdx.x;
    int s = 0;
    for (int j = 0; j < blk; ++j) s += partials[j];
    if (gid < N_NODES) {
        const int o = offsets[gid] + s;
        offsets[gid] = o;
        cursor[gid]  = o;
    }
}

__global__ void fill_kernel(const int* __restrict__ dst, const int* __restrict__ src,
                            const float4* __restrict__ in2,
                            int* __restrict__ cursor, int* __restrict__ edgelist,
                            int* __restrict__ ss, float4* __restrict__ ys) {
    int i = blockIdx.x * blockDim.x + threadIdx.x;
    if (i < N_EDGES) {
        int pos = atomicAdd(&cursor[dst[i]], 1);
        edgelist[pos] = i;
        ss[pos] = src[i];
        ys[pos] = in2[i];
    }
}

// ---------------- main: one block (4 waves) per node, LDS combine ----------------
__global__ __launch_bounds__(256) void tp_node4_kernel(
    const float*  __restrict__ in1,
    const float*  __restrict__ weight,
    const int*    __restrict__ offsets,
    const int*    __restrict__ edgelist,
    const int*    __restrict__ ss,
    const float4* __restrict__ ys,
    float*        __restrict__ out)
{
    __shared__ float sm[4][512];
    const int wave = threadIdx.x >> 6;
    const int lane = threadIdx.x & 63;
    const int n = blockIdx.x;
    const int u = lane & 31;
    const int h = lane >> 5;

    const int start = offsets[n];
    const int end   = (n + 1 < N_NODES) ? offsets[n + 1] : N_EDGES;

    float acc0 = 0.f, acc1 = 0.f, acc2 = 0.f, acc3 = 0.f;
    float acc4 = 0.f, acc5 = 0.f, acc6 = 0.f, acc7 = 0.f;

    // wave handles edges start+wave, start+wave+4, ... ; 2 per iteration
    for (int p0 = start + wave; p0 < end; p0 += 8) {
        const int  p1   = p0 + 4;
        const bool has1 = (p1 < end);
        const int  p1c  = has1 ? p1 : p0;

        // independent index loads
        const int e0 = edgelist[p0];
        const int s0 = ss[p0];
        float4    ya = ys[p0];
        const int e1 = edgelist[p1c];
        const int s1 = ss[p1c];
        float4    yb = ys[p1c];
        if (!has1) { yb.x = 0.f; yb.y = 0.f; yb.z = 0.f; yb.w = 0.f; }

        // independent data loads, all issued before compute
        const float* __restrict__ xA = in1 + (long)s0 * IN1_SIZE;
        const float* __restrict__ wA = weight + (long)e0 * W_SIZE;
        const float* __restrict__ xB = in1 + (long)s1 * IN1_SIZE;
        const float* __restrict__ wB = weight + (long)e1 * W_SIZE;

        const float xsA = xA[lane];
        const float vA0 = xA[64 + 3 * u], vA1 = xA[65 + 3 * u], vA2 = xA[66 + 3 * u];
        const float w1A = wA[lane], w2A = wA[64 + lane];
        const float w3A = wA[128 + u], w4A = wA[160 + u], w5A = wA[192 + u];

        const float xsB = xB[lane];
        const float vB0 = xB[64 + 3 * u], vB1 = xB[65 + 3 * u], vB2 = xB[66 + 3 * u];
        const float w1B = wB[lane], w2B = wB[64 + lane];
        const float w3B = wB[128 + u], w4B = wB[160 + u], w5B = wB[192 + u];

        // edge A
        {
            const float y0 = ya.x, yx = ya.y, yy = ya.z, yz = ya.w;
            acc0 += w1A * xsA * y0;
            const float sw2 = w2A * xsA;
            acc1 += sw2 * yx; acc2 += sw2 * yy; acc3 += sw2 * yz;
            if (h == 0) {
                acc4 += w4A * (vA0 * yx + vA1 * yy + vA2 * yz) * INV_SQRT3;
                const float wy = w3A * y0;
                acc5 += wy * vA0; acc6 += wy * vA1; acc7 += wy * vA2;
            } else {
                const float wc = w5A * INV_SQRT2;
                acc5 += wc * (vA1 * yz - vA2 * yy);
                acc6 += wc * (vA2 * yx - vA0 * yz);
                acc7 += wc * (vA0 * yy - vA1 * yx);
            }
        }
        // edge B (y zeroed if absent -> contributes 0)
        {
            const float y0 = yb.x, yx = yb.y, yy = yb.z, yz = yb.w;
            acc0 += w1B * xsB * y0;
            const float sw2 = w2B * xsB;
            acc1 += sw2 * yx; acc2 += sw2 * yy; acc3 += sw2 * yz;
            if (h == 0) {
                acc4 += w4B * (vB0 * yx + vB1 * yy + vB2 * yz) * INV_SQRT3;
                const float wy = w3B * y0;
                acc5 += wy * vB0; acc6 += wy * vB1; acc7 += wy * vB2;
            } else {
                const float wc = w5B * INV_SQRT2;
                acc5 += wc * (vB1 * yz - vB2 * yy);
                acc6 += wc * (vB2 * yx - vB0 * yz);
                acc7 += wc * (vB0 * yy - vB1 * yx);
            }
        }
    }

    // combine across the 4 waves via LDS
    float* smw = &sm[wave][0];
    smw[0 * 64 + lane] = acc0;
    smw[1 * 64 + lane] = acc1;
    smw[2 * 64 + lane] = acc2;
    smw[3 * 64 + lane] = acc3;
    smw[4 * 64 + lane] = acc4;
    smw[5 * 64 + lane] = acc5;
    smw[6 * 64 + lane] = acc6;
    smw[7 * 64 + lane] = acc7;
    __syncthreads();

    float* __restrict__ row = out + (long)n * OUT_SIZE;
    #pragma unroll
    for (int r = 0; r < 2; ++r) {
        const int s  = threadIdx.x + 256 * r;
        const int j  = s >> 6;
        const int l  = s & 63;
        const int uu = l & 31;
        const int hh = l >> 5;
        const float v = sm[0][s] + sm[1][s] + sm[2][s] + sm[3][s];
        int off;
        bool valid = true;
        if (j == 0)        off = l;
        else if (j <= 3)   off = 96 + 3 * l + (j - 1);
        else if (j == 4) { off = 64 + uu; valid = (hh == 0); }
        else               off = (hh ? 384 : 288) + 3 * uu + (j - 5);
        if (valid) row[off] = v;
    }
}

// ---------------- fallback path (R1, atomics, no ws needed) ----------------
__global__ void zero_out_kernel(float4* __restrict__ out, int n4) {
    const float4 z = make_float4(0.f, 0.f, 0.f, 0.f);
    for (int i = blockIdx.x * blockDim.x + threadIdx.x; i < n4;
         i += gridDim.x * blockDim.x) out[i] = z;
}

__device__ __forceinline__ float edge_val(
    int idx, const float* __restrict__ x, const float* __restrict__ w,
    float y0, float y1x, float y1y, float y1z)
{
    if (idx < 64) {
        return w[idx] * x[idx] * y0;
    } else if (idx < 96) {
        const int u = idx - 64;
        const float a0 = x[64 + 3 * u], a1 = x[65 + 3 * u], a2 = x[66 + 3 * u];
        return w[160 + u] * (a0 * y1x + a1 * y1y + a2 * y1z) * INV_SQRT3;
    } else if (idx < 288) {
        const int t = idx - 96;
        const int i = t / 3;
        const int k = t - 3 * i;
        const float yk = (k == 0) ? y1x : (k == 1) ? y1y : y1z;
        return w[64 + i] * x[i] * yk;
    } else if (idx < 384) {
        const int t = idx - 288;
        const int u = t / 3;
        const int k = t - 3 * u;
        return w[128 + u] * x[64 + 3 * u + k] * y0;
    } else {
        const int t = idx - 384;
        const int u = t / 3;
        const int k = t - 3 * u;
        const float a0 = x[64 + 3 * u], a1 = x[65 + 3 * u], a2 = x[66 + 3 * u];
        float c;
        if (k == 0)      c = a1 * y1z - a2 * y1y;
        else if (k == 1) c = a2 * y1x - a0 * y1z;
        else             c = a0 * y1y - a1 * y1x;
        return w[192 + u] * c * INV_SQRT2;
    }
}

__global__ __launch_bounds__(256) void tp_scatter_kernel(
    const float* __restrict__ in1, const float* __restrict__ in2,
    const float* __restrict__ weight,
    const int* __restrict__ src, const int* __restrict__ dst,
    float* __restrict__ out)
{
    const int wave = threadIdx.x >> 6;
    const int lane = threadIdx.x & 63;
    const int e = blockIdx.x * 4 + wave;
    if (e >= N_EDGES) return;
    const int sn = src[e];
    const int dn = dst[e];
    const float* __restrict__ x = in1 + (long)sn * IN1_SIZE;
    const float* __restrict__ w = weight + (long)e * W_SIZE;
    const float y0  = in2[e * 4 + 0];
    const float y1x = in2[e * 4 + 1];
    const float y1y = in2[e * 4 + 2];
    const float y1z = in2[e * 4 + 3];
    float* __restrict__ o = out + (long)dn * OUT_SIZE;
    #pragma unroll
    for (int j = 0; j < 8; ++j) {
        const int idx = lane + (j << 6);
        if (idx < OUT_SIZE)
            atomicAdd(o + idx, edge_val(idx, x, w, y0, y1x, y1y, y1z));
    }
}

extern "C" void kernel_launch(void* const* d_in, const int* in_sizes, int n_in,
                              void* d_out, int out_size, void* d_ws, size_t ws_size,
                              hipStream_t stream) {
    const float* in1    = (const float*)d_in[0];
    const float* in2    = (const float*)d_in[1];
    const float* weight = (const float*)d_in[2];
    const int*   src    = (const int*)d_in[3];
    const int*   dst    = (const int*)d_in[4];
    float* out = (float*)d_out;

    // ws layout: ys[E] float4 | counts[N] | offsets[N] | cursor[N] | edgelist[E] | ss[E] | partials[64]
    const size_t need = (size_t)N_EDGES * 16 +
                        (size_t)(3 * N_NODES + 2 * N_EDGES + 64) * sizeof(int);
    if (ws_size >= need) {
        float4* ys     = (float4*)d_ws;
        int* counts    = (int*)(ys + N_EDGES);
        int* offsets   = counts + N_NODES;
        int* cursor    = offsets + N_NODES;
        int* edgelist  = cursor + N_NODES;
        int* ss        = edgelist + N_EDGES;
        int* partials  = ss + N_EDGES;

        const int nblk = (N_NODES + 1023) / 1024;   // 49

        hipMemsetAsync(counts, 0, N_NODES * sizeof(int), stream);
        hist_kernel<<<(N_EDGES + 255) / 256, 256, 0, stream>>>(dst, counts);
        scan_blocks_kernel<<<nblk, 1024, 0, stream>>>(counts, offsets, partials);
        add_partials_kernel<<<nblk, 1024, 0, stream>>>(partials, offsets, cursor);
        fill_kernel<<<(N_EDGES + 255) / 256, 256, 0, stream>>>(
            dst, src, (const float4*)in2, cursor, edgelist, ss, ys);

        tp_node4_kernel<<<N_NODES, 256, 0, stream>>>(
            in1, weight, offsets, edgelist, ss, ys, out);
    } else {
        const int n4 = out_size / 4;
        zero_out_kernel<<<2048, 256, 0, stream>>>((float4*)out, n4);
        tp_scatter_kernel<<<(N_EDGES + 3) / 4, 256, 0, stream>>>(
            in1, in2, weight, src, dst, out);
    }
}

// Round 6
// 122.803 us; speedup vs baseline: 2.8708x; 1.2385x over previous
//
#include <hip/hip_runtime.h>

#define N_NODES 50000
#define N_EDGES 200000
#define IN1_SIZE 160
#define W_SIZE 224
#define OUT_SIZE 480
#define INV_SQRT3 0.5773502691896258f
#define INV_SQRT2 0.7071067811865476f

// ---------------- CSR build ----------------
__global__ void hist_kernel(const int* __restrict__ dst, int* __restrict__ counts) {
    int i = blockIdx.x * blockDim.x + threadIdx.x;
    if (i < N_EDGES) atomicAdd(&counts[dst[i]], 1);
}

__global__ __launch_bounds__(1024) void scan_blocks_kernel(
    const int* __restrict__ counts, int* __restrict__ offsets,
    int* __restrict__ partials)
{
    __shared__ int sm[1024];
    const int t = threadIdx.x;
    const int gid = blockIdx.x * 1024 + t;
    const int v = (gid < N_NODES) ? counts[gid] : 0;
    sm[t] = v;
    __syncthreads();
    for (int off = 1; off < 1024; off <<= 1) {
        int a = (t >= off) ? sm[t - off] : 0;
        __syncthreads();
        sm[t] += a;
        __syncthreads();
    }
    if (gid < N_NODES) offsets[gid] = sm[t] - v;
    if (t == 1023) partials[blockIdx.x] = sm[1023];
}

__global__ __launch_bounds__(1024) void add_partials_kernel(
    const int* __restrict__ partials, int* __restrict__ offsets,
    int* __restrict__ cursor)
{
    const int blk = blockIdx.x;
    const int gid = blk * 1024 + threadIdx.x;
    int s = 0;
    for (int j = 0; j < blk; ++j) s += partials[j];
    if (gid < N_NODES) {
        const int o = offsets[gid] + s;
        offsets[gid] = o;
        cursor[gid]  = o;
    }
}

__global__ void fill_kernel(const int* __restrict__ dst, const int* __restrict__ src,
                            const float4* __restrict__ in2,
                            int* __restrict__ cursor, int* __restrict__ edgelist,
                            int* __restrict__ ss, float4* __restrict__ ys) {
    int i = blockIdx.x * blockDim.x + threadIdx.x;
    if (i < N_EDGES) {
        int pos = atomicAdd(&cursor[dst[i]], 1);
        edgelist[pos] = i;
        ss[pos] = src[i];
        ys[pos] = in2[i];
    }
}

// ---------------- main: 4 waves/node, scalar metadata, coalesced loads + shfl ----------------
__global__ __launch_bounds__(256) void tp_node4b_kernel(
    const float*  __restrict__ in1,
    const float*  __restrict__ weight,
    const int*    __restrict__ offsets,
    const int*    __restrict__ edgelist,
    const int*    __restrict__ ss,
    const float4* __restrict__ ys,
    float*        __restrict__ out)
{
    __shared__ float sm[4][512];
    const int wave = threadIdx.x >> 6;
    const int lane = threadIdx.x & 63;
    const int n = blockIdx.x;
    const int u = lane & 31;
    const int h = lane >> 5;

    const int start = offsets[n];
    const int end   = (n + 1 < N_NODES) ? offsets[n + 1] : N_EDGES;

    float acc0 = 0.f, acc1 = 0.f, acc2 = 0.f, acc3 = 0.f;
    float acc4 = 0.f, acc5 = 0.f, acc6 = 0.f, acc7 = 0.f;

    for (int p = start + wave; p < end; p += 4) {
        // wave-uniform metadata via scalar path
        const int pu = __builtin_amdgcn_readfirstlane(p);
        const int e0 = edgelist[pu];
        const int s0 = ss[pu];
        const float4 yv = ys[pu];
        const float y0 = yv.x, yx = yv.y, yy = yv.z, yz = yv.w;

        const float* __restrict__ x = in1 + (long)s0 * IN1_SIZE;
        const float* __restrict__ w = weight + (long)e0 * W_SIZE;

        // 7 coalesced vector loads — each needed line requested exactly once
        const float xs = x[lane];          // s1
        const float a  = x[64 + lane];     // v-block floats 0..63
        const float b  = x[128 + u];       // v-block floats 64..95 (dup across halves)
        const float w1 = w[lane];
        const float w2 = w[64 + lane];
        const float c  = w[128 + lane];    // w3|w4 packed
        const float d  = w[192 + u];       // w5 (dup across halves)

        // v1[u][k] = x[64 + 3u + k], reconstructed via cross-lane shuffles
        float v0, v1, v2;
        {
            const int j0 = 3 * u;
            const float a0 = __shfl(a, j0 & 63);
            const float b0 = __shfl(b, j0 & 63);
            v0 = (j0 < 64) ? a0 : b0;
            const int j1 = j0 + 1;
            const float a1 = __shfl(a, j1 & 63);
            const float b1 = __shfl(b, j1 & 63);
            v1 = (j1 < 64) ? a1 : b1;
            const int j2 = j0 + 2;
            const float a2 = __shfl(a, j2 & 63);
            const float b2 = __shfl(b, j2 & 63);
            v2 = (j2 < 64) ? a2 : b2;
        }
        const float w3 = __shfl(c, u);
        const float w4 = __shfl(c, u + 32);
        const float w5 = __shfl(d, u);

        acc0 += w1 * xs * y0;
        const float sw2 = w2 * xs;
        acc1 += sw2 * yx;
        acc2 += sw2 * yy;
        acc3 += sw2 * yz;
        if (h == 0) {
            acc4 += w4 * (v0 * yx + v1 * yy + v2 * yz) * INV_SQRT3;
            const float wy = w3 * y0;
            acc5 += wy * v0;
            acc6 += wy * v1;
            acc7 += wy * v2;
        } else {
            const float wc = w5 * INV_SQRT2;
            acc5 += wc * (v1 * yz - v2 * yy);
            acc6 += wc * (v2 * yx - v0 * yz);
            acc7 += wc * (v0 * yy - v1 * yx);
        }
    }

    // combine across the 4 waves via LDS
    float* smw = &sm[wave][0];
    smw[0 * 64 + lane] = acc0;
    smw[1 * 64 + lane] = acc1;
    smw[2 * 64 + lane] = acc2;
    smw[3 * 64 + lane] = acc3;
    smw[4 * 64 + lane] = acc4;
    smw[5 * 64 + lane] = acc5;
    smw[6 * 64 + lane] = acc6;
    smw[7 * 64 + lane] = acc7;
    __syncthreads();

    float* __restrict__ row = out + (long)n * OUT_SIZE;
    #pragma unroll
    for (int r = 0; r < 2; ++r) {
        const int s  = threadIdx.x + 256 * r;
        const int j  = s >> 6;
        const int l  = s & 63;
        const int uu = l & 31;
        const int hh = l >> 5;
        const float v = sm[0][s] + sm[1][s] + sm[2][s] + sm[3][s];
        int off;
        bool valid = true;
        if (j == 0)        off = l;
        else if (j <= 3)   off = 96 + 3 * l + (j - 1);
        else if (j == 4) { off = 64 + uu; valid = (hh == 0); }
        else               off = (hh ? 384 : 288) + 3 * uu + (j - 5);
        if (valid) row[off] = v;
    }
}

// ---------------- fallback path (R1, atomics, no ws needed) ----------------
__global__ void zero_out_kernel(float4* __restrict__ out, int n4) {
    const float4 z = make_float4(0.f, 0.f, 0.f, 0.f);
    for (int i = blockIdx.x * blockDim.x + threadIdx.x; i < n4;
         i += gridDim.x * blockDim.x) out[i] = z;
}

__device__ __forceinline__ float edge_val(
    int idx, const float* __restrict__ x, const float* __restrict__ w,
    float y0, float y1x, float y1y, float y1z)
{
    if (idx < 64) {
        return w[idx] * x[idx] * y0;
    } else if (idx < 96) {
        const int u = idx - 64;
        const float a0 = x[64 + 3 * u], a1 = x[65 + 3 * u], a2 = x[66 + 3 * u];
        return w[160 + u] * (a0 * y1x + a1 * y1y + a2 * y1z) * INV_SQRT3;
    } else if (idx < 288) {
        const int t = idx - 96;
        const int i = t / 3;
        const int k = t - 3 * i;
        const float yk = (k == 0) ? y1x : (k == 1) ? y1y : y1z;
        return w[64 + i] * x[i] * yk;
    } else if (idx < 384) {
        const int t = idx - 288;
        const int u = t / 3;
        const int k = t - 3 * u;
        return w[128 + u] * x[64 + 3 * u + k] * y0;
    } else {
        const int t = idx - 384;
        const int u = t / 3;
        const int k = t - 3 * u;
        const float a0 = x[64 + 3 * u], a1 = x[65 + 3 * u], a2 = x[66 + 3 * u];
        float cc;
        if (k == 0)      cc = a1 * y1z - a2 * y1y;
        else if (k == 1) cc = a2 * y1x - a0 * y1z;
        else             cc = a0 * y1y - a1 * y1x;
        return w[192 + u] * cc * INV_SQRT2;
    }
}

__global__ __launch_bounds__(256) void tp_scatter_kernel(
    const float* __restrict__ in1, const float* __restrict__ in2,
    const float* __restrict__ weight,
    const int* __restrict__ src, const int* __restrict__ dst,
    float* __restrict__ out)
{
    const int wave = threadIdx.x >> 6;
    const int lane = threadIdx.x & 63;
    const int e = blockIdx.x * 4 + wave;
    if (e >= N_EDGES) return;
    const int sn = src[e];
    const int dn = dst[e];
    const float* __restrict__ x = in1 + (long)sn * IN1_SIZE;
    const float* __restrict__ w = weight + (long)e * W_SIZE;
    const float y0  = in2[e * 4 + 0];
    const float y1x = in2[e * 4 + 1];
    const float y1y = in2[e * 4 + 2];
    const float y1z = in2[e * 4 + 3];
    float* __restrict__ o = out + (long)dn * OUT_SIZE;
    #pragma unroll
    for (int j = 0; j < 8; ++j) {
        const int idx = lane + (j << 6);
        if (idx < OUT_SIZE)
            atomicAdd(o + idx, edge_val(idx, x, w, y0, y1x, y1y, y1z));
    }
}

extern "C" void kernel_launch(void* const* d_in, const int* in_sizes, int n_in,
                              void* d_out, int out_size, void* d_ws, size_t ws_size,
                              hipStream_t stream) {
    const float* in1    = (const float*)d_in[0];
    const float* in2    = (const float*)d_in[1];
    const float* weight = (const float*)d_in[2];
    const int*   src    = (const int*)d_in[3];
    const int*   dst    = (const int*)d_in[4];
    float* out = (float*)d_out;

    // ws layout: ys[E] float4 | counts[N] | offsets[N] | cursor[N] | edgelist[E] | ss[E] | partials[64]
    const size_t need = (size_t)N_EDGES * 16 +
                        (size_t)(3 * N_NODES + 2 * N_EDGES + 64) * sizeof(int);
    if (ws_size >= need) {
        float4* ys     = (float4*)d_ws;
        int* counts    = (int*)(ys + N_EDGES);
        int* offsets   = counts + N_NODES;
        int* cursor    = offsets + N_NODES;
        int* edgelist  = cursor + N_NODES;
        int* ss        = edgelist + N_EDGES;
        int* partials  = ss + N_EDGES;

        const int nblk = (N_NODES + 1023) / 1024;   // 49

        hipMemsetAsync(counts, 0, N_NODES * sizeof(int), stream);
        hist_kernel<<<(N_EDGES + 255) / 256, 256, 0, stream>>>(dst, counts);
        scan_blocks_kernel<<<nblk, 1024, 0, stream>>>(counts, offsets, partials);
        add_partials_kernel<<<nblk, 1024, 0, stream>>>(partials, offsets, cursor);
        fill_kernel<<<(N_EDGES + 255) / 256, 256, 0, stream>>>(
            dst, src, (const float4*)in2, cursor, edgelist, ss, ys);

        tp_node4b_kernel<<<N_NODES, 256, 0, stream>>>(
            in1, weight, offsets, edgelist, ss, ys, out);
    } else {
        const int n4 = out_size / 4;
        zero_out_kernel<<<2048, 256, 0, stream>>>((float4*)out, n4);
        tp_scatter_kernel<<<(N_EDGES + 3) / 4, 256, 0, stream>>>(
            in1, in2, weight, src, dst, out);
    }
}